// Round 6
// baseline (406.838 us; speedup 1.0000x reference)
//
#include <hip/hip_runtime.h>
#include <hip/hip_bf16.h>

#define N_ENT 100000
#define NB 16
#define DIM 128
#define TILE 64
#define RSTRIDE 132      // 128+4 floats: per-lane b128 reads conflict-free
#define NBLK 1024        // 4 blocks/CU * 256 CU — exactly co-resident (barrier!)
#define N_TILES ((N_ENT + TILE - 1) / TILE)   // 1563
#define SCOPE __HIP_MEMORY_SCOPE_AGENT

// ---------------- kernel 1: head = normalize(ent[e1]) + normalize(rel[r]) ----
__global__ __launch_bounds__(128) void head_kernel(
    const int* __restrict__ e1, const int* __restrict__ rel,
    const float* __restrict__ ent, const float* __restrict__ relemb,
    float* __restrict__ head)
{
    int b = blockIdx.x, d = threadIdx.x;
    float ev = ent[e1[b] * DIM + d];
    float rv = relemb[rel[b] * DIM + d];
    __shared__ float s1[DIM], s2[DIM];
    s1[d] = ev * ev;
    s2[d] = rv * rv;
    __syncthreads();
    for (int s = 64; s > 0; s >>= 1) {
        if (d < s) { s1[d] += s1[d + s]; s2[d] += s2[d + s]; }
        __syncthreads();
    }
    float ne = fmaxf(sqrtf(s1[0]), 1e-12f);
    float nr = fmaxf(sqrtf(s2[0]), 1e-12f);
    head[b * DIM + d] = ev / ne + rv / nr;
}

// ---------------- kernel 2: fused dist + exp + softmax (grid barrier) -------
// 1024 blocks (exactly co-resident: launch_bounds(256,4), LDS 34KB -> 4/CU).
// Phase 1: each block computes exp(dist) for its <=2 tiles, values kept in
// registers; block partial sums stored agent-scope; sharded counter barrier.
// Phase 2: blocks 0..15 reduce one b-row of partials (agent loads — cross-XCD
// L2s hold poison for this region, plain loads would be stale), store rowsum,
// bump flag2. Phase 3: all blocks read rowsums, scale registers, write out
// exactly once (coalesced).
__global__ __launch_bounds__(256, 4) void dist_kernel(
    const float* __restrict__ ent, const float* __restrict__ head,
    float* partials, float* rowsum, unsigned* cnt1, unsigned* flag2,
    float* __restrict__ out)
{
    __shared__ float ldsRow[TILE * RSTRIDE];   // 33792 B
    __shared__ float ldsInv[TILE];             // 256 B
    __shared__ float ldsRed[4];

    const int tid  = threadIdx.x;
    const int lane = tid & 63;
    const int wv   = __builtin_amdgcn_readfirstlane(tid >> 6);  // uniform 0..3
    const int bbase = wv * 4;
    const float4* __restrict__ hg = (const float4*)head;

    float ex[2][4];
    float es0 = 0.f, es1 = 0.f, es2 = 0.f, es3 = 0.f;

    #pragma unroll
    for (int t = 0; t < 2; t++) {
        const int tile = blockIdx.x + t * NBLK;
        if (tile >= N_TILES) {
            ex[t][0] = ex[t][1] = ex[t][2] = ex[t][3] = 0.f;
            continue;
        }
        const int n0 = tile * TILE;
        __syncthreads();   // LDS reuse guard

        // stage rows: 2048 float4, 8 per thread, coalesced global, padded LDS
        {
            const float4* eg = (const float4*)ent;
            #pragma unroll
            for (int i = 0; i < 8; i++) {
                int g = tid + i * 256;
                int r = g >> 5, c = g & 31;
                int gr = n0 + r;
                if (gr >= N_ENT) gr = N_ENT - 1;
                float4 v = eg[gr * (DIM / 4) + c];
                *(float4*)&ldsRow[r * RSTRIDE + c * 4] = v;
            }
        }
        __syncthreads();

        // cooperative row norms: 4 threads per row, 32 floats each
        {
            int r = tid >> 2, q = tid & 3;
            const float* p = &ldsRow[r * RSTRIDE + q * 32];
            float s = 0.f;
            #pragma unroll
            for (int k = 0; k < 8; k++) {
                float4 v = *(const float4*)&p[k * 4];
                s = fmaf(v.x, v.x, s); s = fmaf(v.y, v.y, s);
                s = fmaf(v.z, v.z, s); s = fmaf(v.w, v.w, s);
            }
            s += __shfl_down(s, 2);
            s += __shfl_down(s, 1);
            if (q == 0) ldsInv[r] = 1.0f / fmaxf(sqrtf(s), 1e-12f);
        }
        __syncthreads();

        const float inv = ldsInv[lane];
        const float* rp = &ldsRow[lane * RSTRIDE];

        float a0 = 0.f, a1 = 0.f, a2 = 0.f, a3 = 0.f;
        #pragma unroll 8
        for (int j = 0; j < DIM / 4; j++) {
            float4 v  = *(const float4*)&rp[j * 4];
            float4 q0 = hg[(bbase + 0) * (DIM / 4) + j];   // uniform address
            float4 q1 = hg[(bbase + 1) * (DIM / 4) + j];
            float4 q2 = hg[(bbase + 2) * (DIM / 4) + j];
            float4 q3 = hg[(bbase + 3) * (DIM / 4) + j];
            a0 += fabsf(fmaf(-v.x, inv, q0.x)) + fabsf(fmaf(-v.y, inv, q0.y))
                + fabsf(fmaf(-v.z, inv, q0.z)) + fabsf(fmaf(-v.w, inv, q0.w));
            a1 += fabsf(fmaf(-v.x, inv, q1.x)) + fabsf(fmaf(-v.y, inv, q1.y))
                + fabsf(fmaf(-v.z, inv, q1.z)) + fabsf(fmaf(-v.w, inv, q1.w));
            a2 += fabsf(fmaf(-v.x, inv, q2.x)) + fabsf(fmaf(-v.y, inv, q2.y))
                + fabsf(fmaf(-v.z, inv, q2.z)) + fabsf(fmaf(-v.w, inv, q2.w));
            a3 += fabsf(fmaf(-v.x, inv, q3.x)) + fabsf(fmaf(-v.y, inv, q3.y))
                + fabsf(fmaf(-v.z, inv, q3.z)) + fabsf(fmaf(-v.w, inv, q3.w));
        }

        // exp; no max-subtract needed: dist <= 34, sums < 6e19 << fp32 max
        const bool valid = (n0 + lane) < N_ENT;
        float e0 = valid ? __expf(a0) : 0.f;
        float e1 = valid ? __expf(a1) : 0.f;
        float e2 = valid ? __expf(a2) : 0.f;
        float e3 = valid ? __expf(a3) : 0.f;
        ex[t][0] = e0; ex[t][1] = e1; ex[t][2] = e2; ex[t][3] = e3;
        es0 += e0; es1 += e1; es2 += e2; es3 += e3;
    }

#define WRED(x) { x += __shfl_down(x, 32); x += __shfl_down(x, 16); \
                  x += __shfl_down(x, 8);  x += __shfl_down(x, 4);  \
                  x += __shfl_down(x, 2);  x += __shfl_down(x, 1); }
    WRED(es0) WRED(es1) WRED(es2) WRED(es3)
#undef WRED
    if (lane == 0) {
        __hip_atomic_store(&partials[(bbase + 0) * NBLK + blockIdx.x], es0, __ATOMIC_RELEASE, SCOPE);
        __hip_atomic_store(&partials[(bbase + 1) * NBLK + blockIdx.x], es1, __ATOMIC_RELEASE, SCOPE);
        __hip_atomic_store(&partials[(bbase + 2) * NBLK + blockIdx.x], es2, __ATOMIC_RELEASE, SCOPE);
        __hip_atomic_store(&partials[(bbase + 3) * NBLK + blockIdx.x], es3, __ATOMIC_RELEASE, SCOPE);
    }
    __syncthreads();
    if (tid == 0)
        __hip_atomic_fetch_add(&cnt1[blockIdx.x & 7], 1u, __ATOMIC_ACQ_REL, SCOPE);

    // ---- blocks 0..15: reduce one b-row of partials -> rowsum[b] ----
    if (blockIdx.x < NB) {
        if (tid == 0) {
            long guard = 0;
            for (;;) {
                unsigned s = 0;
                #pragma unroll
                for (int i = 0; i < 8; i++)
                    s += __hip_atomic_load(&cnt1[i], __ATOMIC_ACQUIRE, SCOPE);
                if (s >= NBLK) break;
                __builtin_amdgcn_s_sleep(2);
                if (++guard > (1L << 22)) break;   // no-hang safety net
            }
        }
        __syncthreads();
        const int b = blockIdx.x;
        float s = 0.f;
        for (int k = tid; k < NBLK; k += 256)
            s += __hip_atomic_load(&partials[b * NBLK + k], __ATOMIC_RELAXED, SCOPE);
        s += __shfl_down(s, 32); s += __shfl_down(s, 16);
        s += __shfl_down(s, 8);  s += __shfl_down(s, 4);
        s += __shfl_down(s, 2);  s += __shfl_down(s, 1);
        if (lane == 0) ldsRed[wv] = s;
        __syncthreads();
        if (tid == 0) {
            float tot = ldsRed[0] + ldsRed[1] + ldsRed[2] + ldsRed[3];
            __hip_atomic_store(&rowsum[b], tot, __ATOMIC_RELEASE, SCOPE);
            __hip_atomic_fetch_add(flag2, 1u, __ATOMIC_ACQ_REL, SCOPE);
        }
    }

    // ---- all blocks: wait for the 16 rowsums ----
    if (tid == 0) {
        long guard = 0;
        while (__hip_atomic_load(flag2, __ATOMIC_ACQUIRE, SCOPE) < NB) {
            __builtin_amdgcn_s_sleep(2);
            if (++guard > (1L << 22)) break;       // no-hang safety net
        }
    }
    __syncthreads();

    float sv = 0.f;
    if (lane < 4)
        sv = __hip_atomic_load(&rowsum[bbase + lane], __ATOMIC_RELAXED, SCOPE);
    const float i0 = 1.0f / __shfl(sv, 0);
    const float i1 = 1.0f / __shfl(sv, 1);
    const float i2 = 1.0f / __shfl(sv, 2);
    const float i3 = 1.0f / __shfl(sv, 3);

    #pragma unroll
    for (int t = 0; t < 2; t++) {
        const int tile = blockIdx.x + t * NBLK;
        if (tile >= N_TILES) continue;
        const int n = tile * TILE + lane;
        if (n < N_ENT) {
            out[(bbase + 0) * N_ENT + n] = ex[t][0] * i0;   // coalesced
            out[(bbase + 1) * N_ENT + n] = ex[t][1] * i1;
            out[(bbase + 2) * N_ENT + n] = ex[t][2] * i2;
            out[(bbase + 3) * N_ENT + n] = ex[t][3] * i3;
        }
    }
}

extern "C" void kernel_launch(void* const* d_in, const int* in_sizes, int n_in,
                              void* d_out, int out_size, void* d_ws, size_t ws_size,
                              hipStream_t stream) {
    const int*   e1     = (const int*)d_in[0];
    const int*   rel    = (const int*)d_in[1];
    const float* ent    = (const float*)d_in[4];
    const float* relemb = (const float*)d_in[5];
    float* out = (float*)d_out;

    // ws layout
    float*    head     = (float*)d_ws;                          // 8192 B
    float*    partials = (float*)((char*)d_ws + 8192);          // 16*1024*4 = 65536 B
    float*    rowsum   = (float*)((char*)d_ws + 73728);         // 64 B
    unsigned* cnt1     = (unsigned*)((char*)d_ws + 73792);      // 32 B
    unsigned* flag2    = (unsigned*)((char*)d_ws + 73824);      // 4 B

    // zero only the barrier counters (partials/rowsum are written before read)
    hipMemsetAsync((char*)d_ws + 73792, 0, 36, stream);

    head_kernel<<<16, 128, 0, stream>>>(e1, rel, ent, relemb, head);
    dist_kernel<<<NBLK, 256, 0, stream>>>(ent, head, partials, rowsum,
                                          cnt1, flag2, out);
}

// Round 7
// 126.278 us; speedup vs baseline: 3.2218x; 3.2218x over previous
//
#include <hip/hip_runtime.h>
#include <hip/hip_bf16.h>

#define N_ENT 100000
#define NB 16
#define DIM 128
#define TILE 64
#define RSTRIDE 132      // 128+4 floats: per-lane b128 reads conflict-free
#define N_TILES ((N_ENT + TILE - 1) / TILE)   // 1563

// ---------------- kernel 1: head = normalize(ent[e1]) + normalize(rel[r]) ----
__global__ __launch_bounds__(128) void head_kernel(
    const int* __restrict__ e1, const int* __restrict__ rel,
    const float* __restrict__ ent, const float* __restrict__ relemb,
    float* __restrict__ head)
{
    int b = blockIdx.x, d = threadIdx.x;
    float ev = ent[e1[b] * DIM + d];
    float rv = relemb[rel[b] * DIM + d];
    __shared__ float s1[DIM], s2[DIM];
    s1[d] = ev * ev;
    s2[d] = rv * rv;
    __syncthreads();
    for (int s = 64; s > 0; s >>= 1) {
        if (d < s) { s1[d] += s1[d + s]; s2[d] += s2[d + s]; }
        __syncthreads();
    }
    float ne = fmaxf(sqrtf(s1[0]), 1e-12f);
    float nr = fmaxf(sqrtf(s2[0]), 1e-12f);
    head[b * DIM + d] = ev / ne + rv / nr;
}

// ---------------- kernel 2: fused dist + exp, 8 b per wave ------------------
// 1563 blocks, one 64-entity tile each (dynamic rebalance, no multi-tile
// critical path). Block = 128 thr = 2 waves; wave w computes b in [8w,8w+8)
// for all 64 entities (lane = entity). Each entity row is read from LDS by
// only 2 waves (vs 4 in round 5) and head s_load traffic is halved; total
// VALU math is unchanged. 8 independent accumulators provide ILP to cover
// LDS latency at 2 waves/SIMD.
__global__ __launch_bounds__(128) void dist_kernel(
    const float* __restrict__ ent, const float* __restrict__ head,
    float* __restrict__ partials, float* __restrict__ out)
{
    __shared__ float ldsRow[TILE * RSTRIDE];   // 33792 B
    __shared__ float ldsInv[TILE];             // 256 B

    const int tid  = threadIdx.x;
    const int lane = tid & 63;
    const int wv   = __builtin_amdgcn_readfirstlane(tid >> 6);  // uniform 0..1
    const int bbase = wv * 8;
    const int n0 = blockIdx.x * TILE;
    const float4* __restrict__ hg = (const float4*)head;  // uniform-indexed

    // stage rows: 2048 float4 over 128 threads -> 16 each, coalesced
    {
        const float4* eg = (const float4*)ent;
        #pragma unroll
        for (int i = 0; i < 16; i++) {
            int g = tid + i * 128;             // float4 index within tile
            int r = g >> 5, c = g & 31;
            int gr = n0 + r;
            if (gr >= N_ENT) gr = N_ENT - 1;   // clamp for partial last tile
            float4 v = eg[gr * (DIM / 4) + c];
            *(float4*)&ldsRow[r * RSTRIDE + c * 4] = v;
        }
    }
    __syncthreads();

    // cooperative row norms: 2 threads per row, 64 floats each
    {
        int r = tid >> 1, q = tid & 1;         // rows 0..31 wave0, 32..63 wave1
        const float* p = &ldsRow[r * RSTRIDE + q * 64];
        float s = 0.f;
        #pragma unroll
        for (int k = 0; k < 16; k++) {
            float4 v = *(const float4*)&p[k * 4];
            s = fmaf(v.x, v.x, s); s = fmaf(v.y, v.y, s);
            s = fmaf(v.z, v.z, s); s = fmaf(v.w, v.w, s);
        }
        s += __shfl_down(s, 1);                // pair within same wave
        if (q == 0) ldsInv[r] = 1.0f / fmaxf(sqrtf(s), 1e-12f);
    }
    __syncthreads();

    const float inv = ldsInv[lane];
    const float* rp = &ldsRow[lane * RSTRIDE];

    float acc[8];
    #pragma unroll
    for (int b = 0; b < 8; b++) acc[b] = 0.f;

    for (int j = 0; j < DIM / 4; j++) {
        float4 v = *(const float4*)&rp[j * 4];
        #pragma unroll
        for (int b = 0; b < 8; b++) {
            float4 h = hg[(bbase + b) * (DIM / 4) + j];   // uniform -> s_load
            acc[b] += fabsf(fmaf(-v.x, inv, h.x)) + fabsf(fmaf(-v.y, inv, h.y))
                    + fabsf(fmaf(-v.z, inv, h.z)) + fabsf(fmaf(-v.w, inv, h.w));
        }
    }

    // exp; no max-subtract needed: dist <= 34, sums < 6e19 << fp32 max
    const int n = n0 + lane;
    const bool valid = (n < N_ENT);
    float e[8];
    #pragma unroll
    for (int b = 0; b < 8; b++) {
        e[b] = valid ? __expf(acc[b]) : 0.f;
        if (valid) out[(bbase + b) * N_ENT + n] = e[b];   // coalesced
    }

    // wave-reduce the 8 exp-sums, one store each (no atomics)
    #pragma unroll
    for (int b = 0; b < 8; b++) {
        float s = e[b];
        s += __shfl_down(s, 32); s += __shfl_down(s, 16);
        s += __shfl_down(s, 8);  s += __shfl_down(s, 4);
        s += __shfl_down(s, 2);  s += __shfl_down(s, 1);
        if (lane == 0) partials[(bbase + b) * N_TILES + blockIdx.x] = s;
    }
}

// ---------------- kernel 3: out *= 1/sum(partials[b][*]) --------------------
// Each block redundantly reduces its row's 1563 partials (6.3 KB, L2-hot).
__global__ __launch_bounds__(256) void scale_kernel(
    float* __restrict__ out, const float* __restrict__ partials)
{
    const int b = blockIdx.y;
    const int tid = threadIdx.x;

    // load my output chunk first (overlaps with the reduction)
    const int i = blockIdx.x * 256 + tid;              // float4 index
    float4 v = make_float4(0.f, 0.f, 0.f, 0.f);
    float4* row = (float4*)&out[b * N_ENT];
    const bool valid = (i < N_ENT / 4);
    if (valid) v = row[i];

    float s = 0.f;
    for (int k = tid; k < N_TILES; k += 256) s += partials[b * N_TILES + k];
    s += __shfl_down(s, 32); s += __shfl_down(s, 16);
    s += __shfl_down(s, 8);  s += __shfl_down(s, 4);
    s += __shfl_down(s, 2);  s += __shfl_down(s, 1);
    __shared__ float red[4];
    if ((tid & 63) == 0) red[tid >> 6] = s;
    __syncthreads();
    const float invS = 1.0f / (red[0] + red[1] + red[2] + red[3]);

    if (valid) {
        v.x *= invS; v.y *= invS; v.z *= invS; v.w *= invS;
        row[i] = v;
    }
}

extern "C" void kernel_launch(void* const* d_in, const int* in_sizes, int n_in,
                              void* d_out, int out_size, void* d_ws, size_t ws_size,
                              hipStream_t stream) {
    const int*   e1     = (const int*)d_in[0];
    const int*   rel    = (const int*)d_in[1];
    const float* ent    = (const float*)d_in[4];
    const float* relemb = (const float*)d_in[5];
    float* out = (float*)d_out;

    float* head     = (float*)d_ws;                    // 16*128 f32 = 8192 B
    float* partials = (float*)((char*)d_ws + 8192);    // 16*1563 f32 = 100032 B
    // every partials slot is written before it is read -> no zeroing needed

    head_kernel<<<16, 128, 0, stream>>>(e1, rel, ent, relemb, head);
    dist_kernel<<<N_TILES, 128, 0, stream>>>(ent, head, partials, out);
    scale_kernel<<<dim3((N_ENT / 4 + 255) / 256, NB), 256, 0, stream>>>(out, partials);
}

// Round 8
// 114.564 us; speedup vs baseline: 3.5512x; 1.1022x over previous
//
#include <hip/hip_runtime.h>
#include <hip/hip_bf16.h>

#define N_ENT 100000
#define NB 16
#define DIM 128
#define TILE 64
#define RSTRIDE 132      // 128+4 floats: per-lane b128 reads conflict-free
#define N_TILES ((N_ENT + TILE - 1) / TILE)   // 1563

__device__ __forceinline__ float rdlane(float x, int l) {
    return __int_as_float(__builtin_amdgcn_readlane(__float_as_int(x), l));
}

// ---------------- kernel 1: head = normalize(ent[e1]) + normalize(rel[r]) ----
__global__ __launch_bounds__(128) void head_kernel(
    const int* __restrict__ e1, const int* __restrict__ rel,
    const float* __restrict__ ent, const float* __restrict__ relemb,
    float* __restrict__ head)
{
    int b = blockIdx.x, d = threadIdx.x;
    float ev = ent[e1[b] * DIM + d];
    float rv = relemb[rel[b] * DIM + d];
    __shared__ float s1[DIM], s2[DIM];
    s1[d] = ev * ev;
    s2[d] = rv * rv;
    __syncthreads();
    for (int s = 64; s > 0; s >>= 1) {
        if (d < s) { s1[d] += s1[d + s]; s2[d] += s2[d + s]; }
        __syncthreads();
    }
    float ne = fmaxf(sqrtf(s1[0]), 1e-12f);
    float nr = fmaxf(sqrtf(s2[0]), 1e-12f);
    head[b * DIM + d] = ev / ne + rv / nr;
}

// ---------------- kernel 2: fused dist + exp; heads in VGPRs ----------------
// 1563 blocks, one 64-entity tile each. Block = 4 waves; wave w computes b in
// [4w,4w+4). Heads are loaded ONCE per block into per-lane VGPRs (lane j
// holds head[b][4j..4j+4)) and extracted in the fully-unrolled j-loop via
// v_readlane with literal lane index — pure VALU, no SMEM/VMEM/LDS traffic
// for heads. Hot loop = 1 in-order ds_read_b128 + VALU only.
__global__ __launch_bounds__(256) void dist_kernel(
    const float* __restrict__ ent, const float* __restrict__ head,
    float* __restrict__ partials, float* __restrict__ out)
{
    __shared__ float ldsRow[TILE * RSTRIDE];   // 33792 B
    __shared__ float ldsInv[TILE];             // 256 B

    const int tid  = threadIdx.x;
    const int lane = tid & 63;
    const int wv   = __builtin_amdgcn_readfirstlane(tid >> 6);  // uniform 0..3
    const int bbase = wv * 4;
    const int n0 = blockIdx.x * TILE;

    // heads -> 16 VGPRs/lane: lane j (0..31) holds head[bbase+b][4j..4j+4)
    const float4* hg = (const float4*)head;
    const int Lc = lane & 31;                  // lanes 32-63 mirror 0-31
    float4 H0 = hg[(bbase + 0) * 32 + Lc];
    float4 H1 = hg[(bbase + 1) * 32 + Lc];
    float4 H2 = hg[(bbase + 2) * 32 + Lc];
    float4 H3 = hg[(bbase + 3) * 32 + Lc];

    // stage rows: 2048 float4, 8 per thread, coalesced global, padded LDS
    {
        const float4* eg = (const float4*)ent;
        #pragma unroll
        for (int i = 0; i < 8; i++) {
            int g = tid + i * 256;             // float4 index within tile
            int r = g >> 5, c = g & 31;
            int gr = n0 + r;
            if (gr >= N_ENT) gr = N_ENT - 1;   // clamp for partial last tile
            float4 v = eg[gr * (DIM / 4) + c];
            *(float4*)&ldsRow[r * RSTRIDE + c * 4] = v;
        }
    }
    __syncthreads();

    // cooperative row norms: 4 threads per row, 32 floats each
    {
        int r = tid >> 2, q = tid & 3;
        const float* p = &ldsRow[r * RSTRIDE + q * 32];
        float s = 0.f;
        #pragma unroll
        for (int k = 0; k < 8; k++) {
            float4 v = *(const float4*)&p[k * 4];
            s = fmaf(v.x, v.x, s); s = fmaf(v.y, v.y, s);
            s = fmaf(v.z, v.z, s); s = fmaf(v.w, v.w, s);
        }
        s += __shfl_down(s, 2);
        s += __shfl_down(s, 1);
        if (q == 0) ldsInv[r] = 1.0f / fmaxf(sqrtf(s), 1e-12f);
    }
    __syncthreads();

    const float inv = ldsInv[lane];
    const float* rp = &ldsRow[lane * RSTRIDE];

    float a0 = 0.f, a1 = 0.f, a2 = 0.f, a3 = 0.f;
    #pragma unroll
    for (int j = 0; j < DIM / 4; j++) {       // full unroll -> readlane lane
        float4 v = *(const float4*)&rp[j * 4]; //   index is a literal
        a0 += fabsf(fmaf(-v.x, inv, rdlane(H0.x, j)))
            + fabsf(fmaf(-v.y, inv, rdlane(H0.y, j)))
            + fabsf(fmaf(-v.z, inv, rdlane(H0.z, j)))
            + fabsf(fmaf(-v.w, inv, rdlane(H0.w, j)));
        a1 += fabsf(fmaf(-v.x, inv, rdlane(H1.x, j)))
            + fabsf(fmaf(-v.y, inv, rdlane(H1.y, j)))
            + fabsf(fmaf(-v.z, inv, rdlane(H1.z, j)))
            + fabsf(fmaf(-v.w, inv, rdlane(H1.w, j)));
        a2 += fabsf(fmaf(-v.x, inv, rdlane(H2.x, j)))
            + fabsf(fmaf(-v.y, inv, rdlane(H2.y, j)))
            + fabsf(fmaf(-v.z, inv, rdlane(H2.z, j)))
            + fabsf(fmaf(-v.w, inv, rdlane(H2.w, j)));
        a3 += fabsf(fmaf(-v.x, inv, rdlane(H3.x, j)))
            + fabsf(fmaf(-v.y, inv, rdlane(H3.y, j)))
            + fabsf(fmaf(-v.z, inv, rdlane(H3.z, j)))
            + fabsf(fmaf(-v.w, inv, rdlane(H3.w, j)));
    }

    // exp; no max-subtract needed: dist <= 34, sums < 6e19 << fp32 max
    const int n = n0 + lane;
    const bool valid = (n < N_ENT);
    float e0 = valid ? __expf(a0) : 0.f;
    float e1 = valid ? __expf(a1) : 0.f;
    float e2 = valid ? __expf(a2) : 0.f;
    float e3 = valid ? __expf(a3) : 0.f;
    if (valid) {
        out[(bbase + 0) * N_ENT + n] = e0;     // lane-contiguous: coalesced
        out[(bbase + 1) * N_ENT + n] = e1;
        out[(bbase + 2) * N_ENT + n] = e2;
        out[(bbase + 3) * N_ENT + n] = e3;
    }

#define WRED(x) { x += __shfl_down(x, 32); x += __shfl_down(x, 16); \
                  x += __shfl_down(x, 8);  x += __shfl_down(x, 4);  \
                  x += __shfl_down(x, 2);  x += __shfl_down(x, 1); }
    WRED(e0) WRED(e1) WRED(e2) WRED(e3)
#undef WRED
    if (lane == 0) {   // b-major: partials[b*N_TILES + block] — no contention
        partials[(bbase + 0) * N_TILES + blockIdx.x] = e0;
        partials[(bbase + 1) * N_TILES + blockIdx.x] = e1;
        partials[(bbase + 2) * N_TILES + blockIdx.x] = e2;
        partials[(bbase + 3) * N_TILES + blockIdx.x] = e3;
    }
}

// ---------------- kernel 3: out *= 1/sum(partials[b][*]) --------------------
// Each block redundantly reduces its row's 1563 partials (6.3 KB, L2-hot).
__global__ __launch_bounds__(256) void scale_kernel(
    float* __restrict__ out, const float* __restrict__ partials)
{
    const int b = blockIdx.y;
    const int tid = threadIdx.x;

    // load my output chunk first (overlaps with the reduction)
    const int i = blockIdx.x * 256 + tid;              // float4 index
    float4 v = make_float4(0.f, 0.f, 0.f, 0.f);
    float4* row = (float4*)&out[b * N_ENT];
    const bool valid = (i < N_ENT / 4);
    if (valid) v = row[i];

    float s = 0.f;
    for (int k = tid; k < N_TILES; k += 256) s += partials[b * N_TILES + k];
    s += __shfl_down(s, 32); s += __shfl_down(s, 16);
    s += __shfl_down(s, 8);  s += __shfl_down(s, 4);
    s += __shfl_down(s, 2);  s += __shfl_down(s, 1);
    __shared__ float red[4];
    if ((tid & 63) == 0) red[tid >> 6] = s;
    __syncthreads();
    const float invS = 1.0f / (red[0] + red[1] + red[2] + red[3]);

    if (valid) {
        v.x *= invS; v.y *= invS; v.z *= invS; v.w *= invS;
        row[i] = v;
    }
}

extern "C" void kernel_launch(void* const* d_in, const int* in_sizes, int n_in,
                              void* d_out, int out_size, void* d_ws, size_t ws_size,
                              hipStream_t stream) {
    const int*   e1     = (const int*)d_in[0];
    const int*   rel    = (const int*)d_in[1];
    const float* ent    = (const float*)d_in[4];
    const float* relemb = (const float*)d_in[5];
    float* out = (float*)d_out;

    float* head     = (float*)d_ws;                    // 16*128 f32 = 8192 B
    float* partials = (float*)((char*)d_ws + 8192);    // 16*1563 f32 = 100032 B
    // every partials slot is written before it is read -> no zeroing needed

    head_kernel<<<16, 128, 0, stream>>>(e1, rel, ent, relemb, head);
    dist_kernel<<<N_TILES, 256, 0, stream>>>(ent, head, partials, out);
    scale_kernel<<<dim3((N_ENT / 4 + 255) / 256, NB), 256, 0, stream>>>(out, partials);
}

// Round 9
// 109.122 us; speedup vs baseline: 3.7283x; 1.0499x over previous
//
#include <hip/hip_runtime.h>
#include <hip/hip_bf16.h>

#define N_ENT 100000
#define NB 16
#define DIM 128
#define TILE 64
#define RSTRIDE 132      // 128+4 floats: per-lane b128 reads conflict-free
#define N_TILES ((N_ENT + TILE - 1) / TILE)   // 1563

// ---------------- kernel 1: head = normalize(ent[e1]) + normalize(rel[r]) ----
__global__ __launch_bounds__(128) void head_kernel(
    const int* __restrict__ e1, const int* __restrict__ rel,
    const float* __restrict__ ent, const float* __restrict__ relemb,
    float* __restrict__ head)
{
    int b = blockIdx.x, d = threadIdx.x;
    float ev = ent[e1[b] * DIM + d];
    float rv = relemb[rel[b] * DIM + d];
    __shared__ float s1[DIM], s2[DIM];
    s1[d] = ev * ev;
    s2[d] = rv * rv;
    __syncthreads();
    for (int s = 64; s > 0; s >>= 1) {
        if (d < s) { s1[d] += s1[d + s]; s2[d] += s2[d + s]; }
        __syncthreads();
    }
    float ne = fmaxf(sqrtf(s1[0]), 1e-12f);
    float nr = fmaxf(sqrtf(s2[0]), 1e-12f);
    head[b * DIM + d] = ev / ne + rv / nr;
}

// ---------------- kernel 2: fused dist + exp; 8 waves/block, 2 b per wave ---
// 1563 blocks, one 64-entity tile each. Block = 512 thr = 8 waves; wave w
// computes b in [2w,2w+2) for all 64 entities (lane = entity). LDS 33.8 KB
// -> 4 blocks/CU -> 32 waves/CU = 100% occupancy (2x round 5): TLP covers
// the ds_read->fma dependency chains that stalled the 16-wave/CU versions.
// launch_bounds(512,8) caps VGPR at 64 so 8 waves/SIMD actually fit.
__global__ __launch_bounds__(512, 8) void dist_kernel(
    const float* __restrict__ ent, const float* __restrict__ head,
    float* __restrict__ partials, float* __restrict__ out)
{
    __shared__ float ldsRow[TILE * RSTRIDE];   // 33792 B
    __shared__ float ldsInv[TILE];             // 256 B

    const int tid  = threadIdx.x;
    const int lane = tid & 63;
    const int wv   = __builtin_amdgcn_readfirstlane(tid >> 6);  // uniform 0..7
    const int bbase = wv * 2;
    const int n0 = blockIdx.x * TILE;
    const float4* __restrict__ hg = (const float4*)head;  // uniform-indexed

    // stage rows: 2048 float4 over 512 threads -> 4 each, coalesced
    {
        const float4* eg = (const float4*)ent;
        #pragma unroll
        for (int i = 0; i < 4; i++) {
            int g = tid + i * 512;             // float4 index within tile
            int r = g >> 5, c = g & 31;
            int gr = n0 + r;
            if (gr >= N_ENT) gr = N_ENT - 1;   // clamp for partial last tile
            float4 v = eg[gr * (DIM / 4) + c];
            *(float4*)&ldsRow[r * RSTRIDE + c * 4] = v;
        }
    }
    __syncthreads();

    // cooperative row norms: 8 threads per row, 16 floats each
    {
        int r = tid >> 3, q = tid & 7;
        const float* p = &ldsRow[r * RSTRIDE + q * 16];
        float s = 0.f;
        #pragma unroll
        for (int k = 0; k < 4; k++) {
            float4 v = *(const float4*)&p[k * 4];
            s = fmaf(v.x, v.x, s); s = fmaf(v.y, v.y, s);
            s = fmaf(v.z, v.z, s); s = fmaf(v.w, v.w, s);
        }
        s += __shfl_down(s, 4);
        s += __shfl_down(s, 2);
        s += __shfl_down(s, 1);
        if (q == 0) ldsInv[r] = 1.0f / fmaxf(sqrtf(s), 1e-12f);
    }
    __syncthreads();

    const float inv = ldsInv[lane];
    const float* rp = &ldsRow[lane * RSTRIDE];

    float a0 = 0.f, a1 = 0.f;
    #pragma unroll
    for (int j = 0; j < DIM / 4; j++) {
        float4 v  = *(const float4*)&rp[j * 4];
        float4 q0 = hg[(bbase + 0) * (DIM / 4) + j];   // uniform -> s_load
        float4 q1 = hg[(bbase + 1) * (DIM / 4) + j];
        a0 += fabsf(fmaf(-v.x, inv, q0.x)) + fabsf(fmaf(-v.y, inv, q0.y))
            + fabsf(fmaf(-v.z, inv, q0.z)) + fabsf(fmaf(-v.w, inv, q0.w));
        a1 += fabsf(fmaf(-v.x, inv, q1.x)) + fabsf(fmaf(-v.y, inv, q1.y))
            + fabsf(fmaf(-v.z, inv, q1.z)) + fabsf(fmaf(-v.w, inv, q1.w));
    }

    // exp; no max-subtract needed: dist <= 34, sums < 6e19 << fp32 max
    const int n = n0 + lane;
    const bool valid = (n < N_ENT);
    float e0 = valid ? __expf(a0) : 0.f;
    float e1 = valid ? __expf(a1) : 0.f;
    if (valid) {
        out[(bbase + 0) * N_ENT + n] = e0;     // lane-contiguous: coalesced
        out[(bbase + 1) * N_ENT + n] = e1;
    }

#define WRED(x) { x += __shfl_down(x, 32); x += __shfl_down(x, 16); \
                  x += __shfl_down(x, 8);  x += __shfl_down(x, 4);  \
                  x += __shfl_down(x, 2);  x += __shfl_down(x, 1); }
    WRED(e0) WRED(e1)
#undef WRED
    if (lane == 0) {   // b-major: partials[b*N_TILES + block] — no contention
        partials[(bbase + 0) * N_TILES + blockIdx.x] = e0;
        partials[(bbase + 1) * N_TILES + blockIdx.x] = e1;
    }
}

// ---------------- kernel 3: out *= 1/sum(partials[b][*]) --------------------
// Each block redundantly reduces its row's 1563 partials (6.3 KB, L2-hot).
__global__ __launch_bounds__(256) void scale_kernel(
    float* __restrict__ out, const float* __restrict__ partials)
{
    const int b = blockIdx.y;
    const int tid = threadIdx.x;

    // load my output chunk first (overlaps with the reduction)
    const int i = blockIdx.x * 256 + tid;              // float4 index
    float4 v = make_float4(0.f, 0.f, 0.f, 0.f);
    float4* row = (float4*)&out[b * N_ENT];
    const bool valid = (i < N_ENT / 4);
    if (valid) v = row[i];

    float s = 0.f;
    for (int k = tid; k < N_TILES; k += 256) s += partials[b * N_TILES + k];
    s += __shfl_down(s, 32); s += __shfl_down(s, 16);
    s += __shfl_down(s, 8);  s += __shfl_down(s, 4);
    s += __shfl_down(s, 2);  s += __shfl_down(s, 1);
    __shared__ float red[4];
    if ((tid & 63) == 0) red[tid >> 6] = s;
    __syncthreads();
    const float invS = 1.0f / (red[0] + red[1] + red[2] + red[3]);

    if (valid) {
        v.x *= invS; v.y *= invS; v.z *= invS; v.w *= invS;
        row[i] = v;
    }
}

extern "C" void kernel_launch(void* const* d_in, const int* in_sizes, int n_in,
                              void* d_out, int out_size, void* d_ws, size_t ws_size,
                              hipStream_t stream) {
    const int*   e1     = (const int*)d_in[0];
    const int*   rel    = (const int*)d_in[1];
    const float* ent    = (const float*)d_in[4];
    const float* relemb = (const float*)d_in[5];
    float* out = (float*)d_out;

    float* head     = (float*)d_ws;                    // 16*128 f32 = 8192 B
    float* partials = (float*)((char*)d_ws + 8192);    // 16*1563 f32 = 100032 B
    // every partials slot is written before it is read -> no zeroing needed

    head_kernel<<<16, 128, 0, stream>>>(e1, rel, ent, relemb, head);
    dist_kernel<<<N_TILES, 512, 0, stream>>>(ent, head, partials, out);
    scale_kernel<<<dim3((N_ENT / 4 + 255) / 256, NB), 256, 0, stream>>>(out, partials);
}